// Round 4
// baseline (5112.841 us; speedup 1.0000x reference)
//
#include <hip/hip_runtime.h>
#include <stdint.h>

#define NBLK     1024
#define BLKSZ    256
#define NTH      (NBLK * BLKSZ)      // 262144 threads
#define NPT      8                   // elements per thread
#define TAILT    164992              // tid < TAILT has a valid j==7 element
#define N_SAMP   2000000
#define NSTEP    32
#define INV_N    (1.0 / 2000000.0)
#define NBUCKET  32

#define OUT_BE   2000000
#define OUT_BP   2000204
#define OUT_ETA  2000408
#define OUT_TH   2000606
#define OUT_DH   2000804

struct Keys { unsigned a[NSTEP]; unsigned b[NSTEP]; };

// ---------------- threefry2x32 core cipher, bit-exact vs JAX ----------------
__host__ __device__ inline void threefry2x32(uint32_t k0, uint32_t k1,
                                             uint32_t c0, uint32_t c1,
                                             uint32_t* o0, uint32_t* o1) {
  uint32_t ks2 = k0 ^ k1 ^ 0x1BD11BDAu;
  uint32_t x0 = c0 + k0;
  uint32_t x1 = c1 + k1;
#define TF_ROT(x, d) (((x) << (d)) | ((x) >> (32 - (d))))
#define TF_R(a,b,c,d, ka, kb, inc) \
  x0 += x1; x1 = TF_ROT(x1, a); x1 ^= x0; \
  x0 += x1; x1 = TF_ROT(x1, b); x1 ^= x0; \
  x0 += x1; x1 = TF_ROT(x1, c); x1 ^= x0; \
  x0 += x1; x1 = TF_ROT(x1, d); x1 ^= x0; \
  x0 += (ka); x1 += (kb) + (inc);
  TF_R(13,15,26,6,  k1,  ks2, 1u)
  TF_R(17,29,16,24, ks2, k0,  2u)
  TF_R(13,15,26,6,  k0,  k1,  3u)
  TF_R(17,29,16,24, k1,  ks2, 4u)
  TF_R(13,15,26,6,  ks2, k0,  5u)
#undef TF_R
#undef TF_ROT
  *o0 = x0; *o1 = x1;
}

// bits -> N(0,1), matching jax.random.normal f32 (partitionable bits already XOR-folded)
__device__ inline float bits_to_normal(uint32_t bits) {
  float f = __uint_as_float((bits >> 9) | 0x3f800000u) - 1.0f;
  const float lo = -0.99999994f;
  float u = f * 2.0f + lo;
  u = fmaxf(lo, u);
  float w = -log1pf(-u * u);
  float p;
  if (w < 5.0f) {
    w = w - 2.5f;
    p = 2.81022636e-08f;
    p = fmaf(p, w, 3.43273939e-07f);
    p = fmaf(p, w, -3.5233877e-06f);
    p = fmaf(p, w, -4.39150654e-06f);
    p = fmaf(p, w, 0.00021858087f);
    p = fmaf(p, w, -0.00125372503f);
    p = fmaf(p, w, -0.00417768164f);
    p = fmaf(p, w, 0.246640727f);
    p = fmaf(p, w, 1.50140941f);
  } else {
    w = sqrtf(w) - 3.0f;
    p = -0.000200214257f;
    p = fmaf(p, w, 0.000100950558f);
    p = fmaf(p, w, 0.00134934322f);
    p = fmaf(p, w, -0.00367342844f);
    p = fmaf(p, w, 0.00573950773f);
    p = fmaf(p, w, -0.0076224613f);
    p = fmaf(p, w, 0.00943887047f);
    p = fmaf(p, w, 1.00167406f);
    p = fmaf(p, w, 2.83297682f);
  }
  return __uint_as_float(0x3FB504F3u) * (p * u);
}

__device__ inline void solve6(double G[6][6], double b[6]) {
#pragma unroll
  for (int c = 0; c < 6; c++) {
    double inv = 1.0 / G[c][c];
#pragma unroll
    for (int r = c + 1; r < 6; r++) {
      double fct = G[r][c] * inv;
#pragma unroll
      for (int cc = c + 1; cc < 6; cc++) G[r][cc] -= fct * G[c][cc];
      b[r] -= fct * b[c];
    }
  }
#pragma unroll
  for (int r = 5; r >= 0; r--) {
    double s = b[r];
#pragma unroll
    for (int cc = r + 1; cc < 6; cc++) s -= G[r][cc] * b[cc];
    b[r] = s / G[r][r];
  }
}

__device__ inline double aload(const double* p) {
  return __hip_atomic_load(p, __ATOMIC_RELAXED, __HIP_MEMORY_SCOPE_AGENT);
}
__device__ inline float afload(const float* p) {
  return __hip_atomic_load(p, __ATOMIC_RELAXED, __HIP_MEMORY_SCOPE_AGENT);
}
__device__ inline void afstore(float* p, float v) {
  __hip_atomic_store(p, v, __ATOMIC_RELAXED, __HIP_MEMORY_SCOPE_AGENT);
}

// two-level grid barrier: 32 leaves x 32 blocks, monotone counters (no resets)
__device__ inline void grid_barrier(unsigned* leaf, unsigned* root, unsigned* gen,
                                    int epoch) {
  __syncthreads();
  if (threadIdx.x == 0) {
    int l = blockIdx.x & 31;
    unsigned old = __hip_atomic_fetch_add(&leaf[l], 1u, __ATOMIC_ACQ_REL,
                                          __HIP_MEMORY_SCOPE_AGENT);
    if (old == (unsigned)(epoch * 32 + 31)) {
      unsigned r = __hip_atomic_fetch_add(root, 1u, __ATOMIC_ACQ_REL,
                                          __HIP_MEMORY_SCOPE_AGENT);
      if (r == (unsigned)(epoch * 32 + 31)) {
        __hip_atomic_store(gen, (unsigned)(epoch + 1), __ATOMIC_RELEASE,
                           __HIP_MEMORY_SCOPE_AGENT);
      }
    }
    while (__hip_atomic_load(gen, __ATOMIC_ACQUIRE, __HIP_MEMORY_SCOPE_AGENT)
           <= (unsigned)epoch) {
      __builtin_amdgcn_s_sleep(8);
    }
  }
  __syncthreads();
}

static __device__ const double Bd[7][7] = {
    {1, 0, 0, 0, 0, 0, 0},  {1, 1, 0, 0, 0, 0, 0},   {1, 2, 1, 0, 0, 0, 0},
    {1, 3, 3, 1, 0, 0, 0},  {1, 4, 6, 4, 1, 0, 0},   {1, 5, 10, 10, 5, 1, 0},
    {1, 6, 15, 20, 15, 6, 1}};

__global__ __launch_bounds__(BLKSZ, 4) void k_fused(
    const float* __restrict__ x1g, const float* __restrict__ x0g,
    const float* __restrict__ xkg, const float* __restrict__ tg,
    float* __restrict__ out,
    double* __restrict__ JB, double* __restrict__ SYB, double* __restrict__ SXB,
    float* __restrict__ F, unsigned* __restrict__ bar, Keys keys) {
  __shared__ double sm[4][37];
  __shared__ double Msc[37];
  __shared__ double prevSx[10], prevSy[10];
  __shared__ float cP[8], cC[8];

  const int tid = blockIdx.x * BLKSZ + threadIdx.x;
  const int lane = threadIdx.x & 63;
  const int wid = threadIdx.x >> 6;
  const int bidx = blockIdx.x & (NBUCKET - 1);
  unsigned* leaf = bar;
  unsigned* root = bar + 32;
  unsigned* gen  = bar + 33;
  int epoch = 0;

  if (threadIdx.x < 10) { prevSx[threadIdx.x] = 0.0; prevSy[threadIdx.x] = 0.0; }
  __syncthreads();

  // ================= Phase J: 27 joint (x0,x1) moments + 10 x_k moments =====
  {
    double acc[37];
#pragma unroll
    for (int q = 0; q < 37; q++) acc[q] = 0.0;
#pragma unroll
    for (int j = 0; j < NPT; j++) {
      int idx = j * NTH + tid;
      if (j < 7 || tid < TAILT) {
        float a0 = x0g[idx], a1 = x1g[idx], xk = xkg[idx];
        float p0[7], p1[7];
        p0[0] = 1.f; p1[0] = 1.f;
#pragma unroll
        for (int m = 0; m < 6; m++) { p0[m + 1] = p0[m] * a0; p1[m + 1] = p1[m] * a1; }
        int q = 0;
#pragma unroll
        for (int s = 1; s <= 6; s++)
#pragma unroll
          for (int a = 0; a <= s; a++) acc[q++] += (double)(p0[a] * p1[s - a]);
        float xp = xk;
        acc[27] += (double)xp;
#pragma unroll
        for (int m = 1; m < 10; m++) { xp *= xk; acc[27 + m] += (double)xp; }
      }
    }
    // block reduce -> bucketed atomics
    {
#pragma unroll
      for (int q = 0; q < 37; q++) {
        double v = acc[q];
#pragma unroll
        for (int off = 32; off; off >>= 1) v += __shfl_down(v, off, 64);
        if (lane == 0) sm[wid][q] = v;
      }
      __syncthreads();
      if (threadIdx.x < 37) {
        double s = sm[0][threadIdx.x] + sm[1][threadIdx.x] +
                   sm[2][threadIdx.x] + sm[3][threadIdx.x];
        atomicAdd(&JB[threadIdx.x * NBUCKET + bidx], s);
      }
    }
  }
  grid_barrier(leaf, root, gen, epoch); epoch++;

  // ================= Phase F: per-step scalar table (blocks 0..31, wave 0) ==
  if (blockIdx.x < NSTEP && wid == 0) {
    for (int q = 0; q < 37; q++) {
      double v = (lane < NBUCKET) ? aload(&JB[q * NBUCKET + lane]) : 0.0;
#pragma unroll
      for (int off = 16; off; off >>= 1) v += __shfl_down(v, off, 64);
      if (lane == 0) Msc[q] = v;
    }
    int k = blockIdx.x;
    float tk = tg[k], tk1 = tg[k + 1];
    float h = tk1 - tk;
    float ns = sqrtf(2.0f * h) * 0.5f;
    const float PI_F = 3.14159274f;
    double a  = (double)cosf((PI_F * tk) * 0.5f);
    double b  = (double)sinf((PI_F * tk) * 0.5f);
    double a1 = (double)cosf((PI_F * tk1) * 0.5f);
    double b1 = (double)sinf((PI_F * tk1) * 0.5f);
    const double C2 = (double)1.57079637f;
    double pa[7], pb[7], pa1[7], pb1[7];
    pa[0] = pb[0] = pa1[0] = pb1[0] = 1.0;
    for (int i = 1; i < 7; i++) {
      pa[i] = pa[i - 1] * a;   pb[i] = pb[i - 1] * b;
      pa1[i] = pa1[i - 1] * a1; pb1[i] = pb1[i - 1] * b1;
    }
    // Mg(a,b) = mean(x0^a x1^b)
#define MG(A, B_) (((A) == 0 && (B_) == 0) ? 1.0 : \
    Msc[(((A) + (B_) + 2) * ((A) + (B_) - 1)) / 2 + (A)] * INV_N)
    float fr[6], fb[6], fd[6];
    for (int p = 1; p <= 6; p++) {
      double s_rhs = 0, s_bpe = 0, s_dt = 0;
      for (int j = 0; j < p; j++) {
        double term = -b * MG(j + 1, p - 1 - j) + a * MG(j, p - j);
        s_rhs += Bd[p - 1][j] * pa[j]  * pb[p - 1 - j]  * term;
        s_dt  += Bd[p - 1][j] * pa1[j] * pb1[p - 1 - j] * term;
      }
      for (int j = 0; j <= p; j++) s_bpe += Bd[p][j] * pa1[j] * pb1[p - j] * MG(j, p - j);
      fr[p - 1] = (float)((double)p * C2 * s_rhs);
      fb[p - 1] = (float)s_bpe;
      fd[p - 1] = (float)((double)p * C2 * s_dt);
    }
    if (lane == 0) {
      afstore(&F[k * 20 + 0], h);
      afstore(&F[k * 20 + 1], ns);
      for (int i = 0; i < 6; i++) {
        afstore(&F[k * 20 + 2 + i], fr[i]);
        afstore(&F[k * 20 + 8 + i], fb[i]);
        afstore(&F[k * 20 + 14 + i], fd[i]);
      }
      if (k == 0) {  // row 0 of barphi_e (x0 moments) and barphi_p (xk moments)
        for (int p = 1; p <= 6; p++) {
          out[OUT_BE + (p - 1)] = (float)(MG(p, 0));
          out[OUT_BP + (p - 1)] = (float)(Msc[27 + (p - 1)] * INV_N);
        }
      }
    }
#undef MG
  }
  grid_barrier(leaf, root, gen, epoch); epoch++;

  // ================= load state into registers ==============================
  float xr[NPT];
#pragma unroll
  for (int j = 0; j < NPT; j++) {
    int idx = j * NTH + tid;
    xr[j] = (j < 7 || tid < TAILT) ? xkg[idx] : 0.0f;
  }

  // ================= main 32-step loop ======================================
  for (int k = 0; k < NSTEP; k++) {
    // ---- predictor solve (wave 0) ----
    if (wid == 0) {
      const double* base = (k == 0) ? (JB + 27 * NBUCKET) : SXB;
      for (int q = 0; q < 10; q++) {
        double v = (lane < NBUCKET) ? aload(&base[q * NBUCKET + lane]) : 0.0;
#pragma unroll
        for (int off = 16; off; off >>= 1) v += __shfl_down(v, off, 64);
        if (lane == 0) Msc[q] = v;
      }
      double d[10];
#pragma unroll
      for (int q = 0; q < 10; q++) {
        double tot = Msc[q];
        d[q] = (k == 0) ? tot : (tot - prevSx[q]);
      }
      if (k > 0 && lane < 10) prevSx[lane] = Msc[lane];
      double S[11];
      S[0] = 1.0;
#pragma unroll
      for (int m = 0; m < 10; m++) S[m + 1] = d[m] * INV_N;
      double G[6][6];
#pragma unroll
      for (int i = 0; i < 6; i++)
#pragma unroll
        for (int j = 0; j < 6; j++) G[i][j] = (double)((i + 1) * (j + 1)) * S[i + j];
#pragma unroll
      for (int i = 0; i < 6; i++) G[i][i] *= 1.001;
      double rhs[6];
#pragma unroll
      for (int i = 0; i < 6; i++) rhs[i] = (double)afload(&F[k * 20 + 2 + i]);
      solve6(G, rhs);
      if (lane == 0) {
        cP[6] = afload(&F[k * 20 + 0]);
        cP[7] = afload(&F[k * 20 + 1]);
      }
      if (lane < 6) cP[lane] = (float)rhs[lane] * (float)(lane + 1);
      if (blockIdx.x == 0) {
        if (lane < 6) {
          float v = (float)rhs[lane];
          out[OUT_ETA + k * 6 + lane] = v;
          if (k == NSTEP - 1) out[OUT_ETA + NSTEP * 6 + lane] = v;
        }
        if (k > 0 && lane < 6) out[OUT_BP + k * 6 + lane] = (float)(d[lane] * INV_N);
      }
    }
    __syncthreads();

    // ---- predictor elementwise (state in regs), accumulate S(y) ----
    {
      float h = cP[6], ns = cP[7];
      float c0 = cP[0], c1 = cP[1], c2 = cP[2], c3 = cP[3], c4 = cP[4], c5 = cP[5];
      double acc[10];
#pragma unroll
      for (int q = 0; q < 10; q++) acc[q] = 0.0;
#pragma unroll
      for (int j = 0; j < NPT; j++) {
        int idx = j * NTH + tid;
        if (j < 7 || tid < TAILT) {
          uint32_t o0, o1;
          threefry2x32(keys.a[k], keys.b[k], 0u, (uint32_t)idx, &o0, &o1);
          float nz = bits_to_normal(o0 ^ o1);
          float xv = xr[j];
          float dv = c0 + xv * (c1 + xv * (c2 + xv * (c3 + xv * (c4 + xv * c5))));
          float y = xv + h * dv + ns * nz;
          xr[j] = y;
          float pw = y;
          acc[0] += (double)pw;
#pragma unroll
          for (int m = 1; m < 10; m++) { pw *= y; acc[m] += (double)pw; }
        }
      }
#pragma unroll
      for (int q = 0; q < 10; q++) {
        double v = acc[q];
#pragma unroll
        for (int off = 32; off; off >>= 1) v += __shfl_down(v, off, 64);
        if (lane == 0) sm[wid][q] = v;
      }
      __syncthreads();
      if (threadIdx.x < 10) {
        double s = sm[0][threadIdx.x] + sm[1][threadIdx.x] +
                   sm[2][threadIdx.x] + sm[3][threadIdx.x];
        atomicAdd(&SYB[threadIdx.x * NBUCKET + bidx], s);
      }
    }
    grid_barrier(leaf, root, gen, epoch); epoch++;

    // ---- corrector solve (wave 0) ----
    if (wid == 0) {
      for (int q = 0; q < 10; q++) {
        double v = (lane < NBUCKET) ? aload(&SYB[q * NBUCKET + lane]) : 0.0;
#pragma unroll
        for (int off = 16; off; off >>= 1) v += __shfl_down(v, off, 64);
        if (lane == 0) Msc[q] = v;
      }
      double d[10];
#pragma unroll
      for (int q = 0; q < 10; q++) d[q] = Msc[q] - prevSy[q];
      if (lane < 10) prevSy[lane] = Msc[lane];
      double S[11];
      S[0] = 1.0;
#pragma unroll
      for (int m = 0; m < 10; m++) S[m + 1] = d[m] * INV_N;
      double G[6][6];
#pragma unroll
      for (int i = 0; i < 6; i++)
#pragma unroll
        for (int j = 0; j < 6; j++) G[i][j] = (double)((i + 1) * (j + 1)) * S[i + j];
#pragma unroll
      for (int i = 0; i < 6; i++) G[i][i] *= 1.001;
      double rhs[6];
#pragma unroll
      for (int i = 0; i < 6; i++)
        rhs[i] = (double)afload(&F[k * 20 + 8 + i]) - d[i] * INV_N;
      solve6(G, rhs);
      if (lane < 6) cC[lane] = (float)rhs[lane] * (float)(lane + 1);
      if (blockIdx.x == 0) {
        if (lane == 0) {
          float denom = cP[6] * 0.25f;  // h * SIGMA^2
          float dH = 0.f;
          for (int i = 0; i < 6; i++) {
            float th = (float)rhs[i] / denom;
            out[OUT_TH + k * 6 + i] = th;
            if (k == NSTEP - 1) out[OUT_TH + NSTEP * 6 + i] = th;
            dH += th * afload(&F[k * 20 + 14 + i]);
          }
          dH = -dH;
          out[OUT_DH + k] = dH;
          if (k == NSTEP - 1) out[OUT_DH + NSTEP] = dH;
        }
        if (lane < 6) {
          float be = afload(&F[k * 20 + 8 + lane]);
          out[OUT_BE + (k + 1) * 6 + lane] = be;
          if (k == NSTEP - 1) out[OUT_BE + (NSTEP + 1) * 6 + lane] = be;
        }
      }
    }
    __syncthreads();

    // ---- corrector elementwise, accumulate S(x_next) ----
    {
      float c0 = cC[0], c1 = cC[1], c2 = cC[2], c3 = cC[3], c4 = cC[4], c5 = cC[5];
      double acc[10];
#pragma unroll
      for (int q = 0; q < 10; q++) acc[q] = 0.0;
#pragma unroll
      for (int j = 0; j < NPT; j++) {
        if (j < 7 || tid < TAILT) {
          float y = xr[j];
          float cr = c0 + y * (c1 + y * (c2 + y * (c3 + y * (c4 + y * c5))));
          float xn = y + cr;
          xr[j] = xn;
          float pw = xn;
          acc[0] += (double)pw;
#pragma unroll
          for (int m = 1; m < 10; m++) { pw *= xn; acc[m] += (double)pw; }
        }
      }
#pragma unroll
      for (int q = 0; q < 10; q++) {
        double v = acc[q];
#pragma unroll
        for (int off = 32; off; off >>= 1) v += __shfl_down(v, off, 64);
        if (lane == 0) sm[wid][q] = v;
      }
      __syncthreads();
      if (threadIdx.x < 10) {
        double s = sm[0][threadIdx.x] + sm[1][threadIdx.x] +
                   sm[2][threadIdx.x] + sm[3][threadIdx.x];
        atomicAdd(&SXB[threadIdx.x * NBUCKET + bidx], s);
      }
    }
    grid_barrier(leaf, root, gen, epoch); epoch++;
  }

  // ================= write x_final ==========================================
#pragma unroll
  for (int j = 0; j < NPT; j++) {
    int idx = j * NTH + tid;
    if (j < 7 || tid < TAILT) out[idx] = xr[j];
  }
  // barphi_p rows 32, 33 (moments of x_final)
  if (blockIdx.x == 0 && wid == 0) {
    for (int q = 0; q < 6; q++) {
      double v = (lane < NBUCKET) ? aload(&SXB[q * NBUCKET + lane]) : 0.0;
#pragma unroll
      for (int off = 16; off; off >>= 1) v += __shfl_down(v, off, 64);
      if (lane == 0) Msc[q] = v;
    }
    if (lane < 6) {
      float bp = (float)((Msc[lane] - prevSx[lane]) * INV_N);
      out[OUT_BP + NSTEP * 6 + lane] = bp;
      out[OUT_BP + (NSTEP + 1) * 6 + lane] = bp;
    }
  }
}

extern "C" void kernel_launch(void* const* d_in, const int* in_sizes, int n_in,
                              void* d_out, int out_size, void* d_ws, size_t ws_size,
                              hipStream_t stream) {
  const float* x1 = (const float*)d_in[0];
  const float* x0 = (const float*)d_in[1];
  const float* xk = (const float*)d_in[2];
  const float* t  = (const float*)d_in[3];
  float* out = (float*)d_out;

  // ws layout (17288 bytes total)
  double* JB  = (double*)d_ws;          // 37*32 joint-moment buckets
  double* SYB = JB + 37 * NBUCKET;      // 10*32 cumulative y-moment buckets
  double* SXB = SYB + 10 * NBUCKET;     // 10*32 cumulative x-moment buckets
  float*  F   = (float*)(SXB + 10 * NBUCKET);  // 32*20 per-step scalars
  unsigned* bar = (unsigned*)(F + 640); // leaf[32], root, gen

  hipMemsetAsync(d_ws, 0, (size_t)((37 + 10 + 10) * NBUCKET * 8 + 640 * 4 + 34 * 4),
                 stream);

  Keys keys;
  for (int k = 0; k < NSTEP; k++)
    threefry2x32(0u, 42u, 0u, (uint32_t)k, &keys.a[k], &keys.b[k]);

  k_fused<<<NBLK, BLKSZ, 0, stream>>>(x1, x0, xk, t, out, JB, SYB, SXB, F, bar, keys);
}

// Round 5
// 4499.023 us; speedup vs baseline: 1.1364x; 1.1364x over previous
//
#include <hip/hip_runtime.h>
#include <stdint.h>

#define N_SAMP   2000000
#define NSTEP    32
#define INV_N    (1.0 / 2000000.0)
#define NB       256            // reduction buckets
#define GRID     7813           // ceil(2e6/256)
#define BLKSZ    256

#define OUT_BE   2000000
#define OUT_BP   2000204
#define OUT_ETA  2000408
#define OUT_TH   2000606
#define OUT_DH   2000804

// ---------------- threefry2x32 core cipher, bit-exact vs JAX ----------------
__host__ __device__ inline void threefry2x32(uint32_t k0, uint32_t k1,
                                             uint32_t c0, uint32_t c1,
                                             uint32_t* o0, uint32_t* o1) {
  uint32_t ks2 = k0 ^ k1 ^ 0x1BD11BDAu;
  uint32_t x0 = c0 + k0;
  uint32_t x1 = c1 + k1;
#define TF_ROT(x, d) (((x) << (d)) | ((x) >> (32 - (d))))
#define TF_R(a,b,c,d, ka, kb, inc) \
  x0 += x1; x1 = TF_ROT(x1, a); x1 ^= x0; \
  x0 += x1; x1 = TF_ROT(x1, b); x1 ^= x0; \
  x0 += x1; x1 = TF_ROT(x1, c); x1 ^= x0; \
  x0 += x1; x1 = TF_ROT(x1, d); x1 ^= x0; \
  x0 += (ka); x1 += (kb) + (inc);
  TF_R(13,15,26,6,  k1,  ks2, 1u)
  TF_R(17,29,16,24, ks2, k0,  2u)
  TF_R(13,15,26,6,  k0,  k1,  3u)
  TF_R(17,29,16,24, k1,  ks2, 4u)
  TF_R(13,15,26,6,  ks2, k0,  5u)
#undef TF_R
#undef TF_ROT
  *o0 = x0; *o1 = x1;
}

// bits -> N(0,1), jax.random.normal f32 path (partitionable bits pre-XOR-folded)
__device__ inline float bits_to_normal(uint32_t bits) {
  float f = __uint_as_float((bits >> 9) | 0x3f800000u) - 1.0f;
  const float lo = -0.99999994f;
  float u = f * 2.0f + lo;
  u = fmaxf(lo, u);
  float w = -log1pf(-u * u);
  float p;
  if (w < 5.0f) {
    w = w - 2.5f;
    p = 2.81022636e-08f;
    p = fmaf(p, w, 3.43273939e-07f);
    p = fmaf(p, w, -3.5233877e-06f);
    p = fmaf(p, w, -4.39150654e-06f);
    p = fmaf(p, w, 0.00021858087f);
    p = fmaf(p, w, -0.00125372503f);
    p = fmaf(p, w, -0.00417768164f);
    p = fmaf(p, w, 0.246640727f);
    p = fmaf(p, w, 1.50140941f);
  } else {
    w = sqrtf(w) - 3.0f;
    p = -0.000200214257f;
    p = fmaf(p, w, 0.000100950558f);
    p = fmaf(p, w, 0.00134934322f);
    p = fmaf(p, w, -0.00367342844f);
    p = fmaf(p, w, 0.00573950773f);
    p = fmaf(p, w, -0.0076224613f);
    p = fmaf(p, w, 0.00943887047f);
    p = fmaf(p, w, 1.00167406f);
    p = fmaf(p, w, 2.83297682f);
  }
  return __uint_as_float(0x3FB504F3u) * (p * u);
}

// ---------------------------------------------------------------------------
// Wave-0 lane-distributed 6x6 solve. Lane r (r<6) ends with xv = solution[r].
// B: 10 quantities x 256 buckets (f64 partial sums of moments 1..10).
// Also returns replicated mean-moments S[1..10] (all lanes).
// rhs per-lane value supplied by caller in rv (lane<6).
// ---------------------------------------------------------------------------
__device__ inline double wave_solve6(const double* __restrict__ B, int lane,
                                     double S[11], double rv) {
  S[0] = 1.0;
#pragma unroll
  for (int q = 0; q < 10; q++) {
    const double* p = B + q * NB + lane;
    double s = p[0] + p[64] + p[128] + p[192];
#pragma unroll
    for (int off = 32; off; off >>= 1) s += __shfl_xor(s, off, 64);
    S[q + 1] = s * INV_N;
  }
  int r = (lane < 6) ? lane : 0;
  double row[6];
#pragma unroll
  for (int j = 0; j < 6; j++) row[j] = (double)((r + 1) * (j + 1)) * S[r + j];
  row[r] *= 1.001;                       // REG = (1e-3, 0, 0)
  // forward elimination (no pivoting; G SPD)
#pragma unroll
  for (int c = 0; c < 6; c++) {
    double pr[6], prh;
#pragma unroll
    for (int j = 0; j < 6; j++) pr[j] = __shfl(row[j], c, 64);
    prh = __shfl(rv, c, 64);
    if (lane > c && lane < 6) {
      double f = row[c] / pr[c];
#pragma unroll
      for (int j = 0; j < 6; j++) row[j] -= f * pr[j];
      rv -= f * prh;
    }
  }
  // back substitution
  double xv = 0.0;
#pragma unroll
  for (int rr = 5; rr >= 0; rr--) {
    double cand = rv / row[rr];
    double xr = __shfl(cand, rr, 64);
    if (lane == rr) xv = xr;
    if (lane < rr) rv -= row[rr] * xr;
  }
  return xv;
}

// block-reduce 10 f64 (m[]) -> bucketed atomics
__device__ inline void reduce10(double m[10], double* __restrict__ buck,
                                int lane, int wid, double sm[4][10]) {
#pragma unroll
  for (int q = 0; q < 10; q++) {
    double v = m[q];
#pragma unroll
    for (int off = 32; off; off >>= 1) v += __shfl_down(v, off, 64);
    if (lane == 0) sm[wid][q] = v;
  }
  __syncthreads();
  if (threadIdx.x < 10) {
    double s = sm[0][threadIdx.x] + sm[1][threadIdx.x] +
               sm[2][threadIdx.x] + sm[3][threadIdx.x];
    atomicAdd(&buck[threadIdx.x * NB + (blockIdx.x & (NB - 1))], s);
  }
}

// ================= setup reduction: 27 joint (x0,x1) + 10 x_k moments =======
__global__ __launch_bounds__(BLKSZ) void k_reduce0(
    const float* __restrict__ x1g, const float* __restrict__ x0g,
    const float* __restrict__ xkg, double* __restrict__ JB) {
  __shared__ double sm[4][37];
  int i = blockIdx.x * BLKSZ + threadIdx.x;
  int lane = threadIdx.x & 63, wid = threadIdx.x >> 6;
  double a37[37];
  if (i < N_SAMP) {
    float a0 = x0g[i], a1 = x1g[i], xk = xkg[i];
    float p0[7], p1[7];
    p0[0] = 1.f; p1[0] = 1.f;
#pragma unroll
    for (int m = 0; m < 6; m++) { p0[m + 1] = p0[m] * a0; p1[m + 1] = p1[m] * a1; }
    int q = 0;
#pragma unroll
    for (int s = 1; s <= 6; s++)
#pragma unroll
      for (int a = 0; a <= s; a++) a37[q++] = (double)(p0[a] * p1[s - a]);
    float xp = xk;
    a37[27] = (double)xp;
#pragma unroll
    for (int m = 1; m < 10; m++) { xp *= xk; a37[27 + m] = (double)xp; }
  } else {
#pragma unroll
    for (int q = 0; q < 37; q++) a37[q] = 0.0;
  }
#pragma unroll
  for (int q = 0; q < 37; q++) {
    double v = a37[q];
#pragma unroll
    for (int off = 32; off; off >>= 1) v += __shfl_down(v, off, 64);
    if (lane == 0) sm[wid][q] = v;
  }
  __syncthreads();
  if (threadIdx.x < 37) {
    double s = sm[0][threadIdx.x] + sm[1][threadIdx.x] +
               sm[2][threadIdx.x] + sm[3][threadIdx.x];
    atomicAdd(&JB[threadIdx.x * NB + (blockIdx.x & (NB - 1))], s);
  }
}

// ================= per-step scalar table + be rows + row0 ===================
__global__ void k_scalars(const float* __restrict__ tg,
                          const double* __restrict__ JB,
                          float* __restrict__ F, float* __restrict__ out) {
  __shared__ double Msc[37];
  int lane = threadIdx.x & 63;
  for (int q = 0; q < 37; q++) {
    const double* p = JB + q * NB + lane * 4;
    double s = p[0] + p[1] + p[2] + p[3];
#pragma unroll
    for (int off = 32; off; off >>= 1) s += __shfl_xor(s, off, 64);
    if (lane == 0) Msc[q] = s * INV_N;
  }
  __syncthreads();
#define MG(A, B_) (((A) == 0 && (B_) == 0) ? 1.0 : \
    Msc[(((A) + (B_) + 2) * ((A) + (B_) - 1)) / 2 + (A)])
  int k = threadIdx.x;
  if (k < NSTEP) {
    const double Bd[7][7] = {
        {1, 0, 0, 0, 0, 0, 0},  {1, 1, 0, 0, 0, 0, 0},   {1, 2, 1, 0, 0, 0, 0},
        {1, 3, 3, 1, 0, 0, 0},  {1, 4, 6, 4, 1, 0, 0},   {1, 5, 10, 10, 5, 1, 0},
        {1, 6, 15, 20, 15, 6, 1}};
    float tk = tg[k], tk1 = tg[k + 1];
    float h = tk1 - tk;
    float ns = sqrtf(2.0f * h) * 0.5f;
    const float PI_F = 3.14159274f;
    double a  = (double)cosf((PI_F * tk) * 0.5f);
    double b  = (double)sinf((PI_F * tk) * 0.5f);
    double a1 = (double)cosf((PI_F * tk1) * 0.5f);
    double b1 = (double)sinf((PI_F * tk1) * 0.5f);
    const double C2 = (double)1.57079637f;
    double pa[7], pb[7], pa1[7], pb1[7];
    pa[0] = pb[0] = pa1[0] = pb1[0] = 1.0;
    for (int i = 1; i < 7; i++) {
      pa[i] = pa[i - 1] * a;    pb[i] = pb[i - 1] * b;
      pa1[i] = pa1[i - 1] * a1; pb1[i] = pb1[i - 1] * b1;
    }
    F[k * 20 + 0] = h;
    F[k * 20 + 1] = ns;
    for (int p = 1; p <= 6; p++) {
      double s_rhs = 0, s_bpe = 0, s_dt = 0;
      for (int j = 0; j < p; j++) {
        double term = -b * MG(j + 1, p - 1 - j) + a * MG(j, p - j);
        s_rhs += Bd[p - 1][j] * pa[j]  * pb[p - 1 - j]  * term;
        s_dt  += Bd[p - 1][j] * pa1[j] * pb1[p - 1 - j] * term;
      }
      for (int j = 0; j <= p; j++)
        s_bpe += Bd[p][j] * pa1[j] * pb1[p - j] * MG(j, p - j);
      F[k * 20 + 2 + p - 1]  = (float)((double)p * C2 * s_rhs);
      float be = (float)s_bpe;
      F[k * 20 + 8 + p - 1]  = be;
      F[k * 20 + 14 + p - 1] = (float)((double)p * C2 * s_dt);
      out[OUT_BE + (k + 1) * 6 + (p - 1)] = be;
      if (k == NSTEP - 1) out[OUT_BE + (NSTEP + 1) * 6 + (p - 1)] = be;
    }
  }
  if (threadIdx.x < 6) {  // row 0: moments of x_0 and of x_k
    int p = threadIdx.x + 1;
    out[OUT_BE + threadIdx.x] = (float)MG(p, 0);
    out[OUT_BP + threadIdx.x] = (float)Msc[27 + threadIdx.x];
  }
#undef MG
}

// ================= predictor step k =========================================
// y[i] = x[i] + h*poly(x) + ns*noise ; accumulate S(y) into SYB.
// wave0 solves eta from SxB; block0 writes eta row (and bp row k for k>=1).
__global__ __launch_bounds__(BLKSZ) void k_pred(
    const float* xin, float* yout,
    const double* __restrict__ SxB, const float* __restrict__ F,
    double* __restrict__ SYB, float* __restrict__ out,
    uint32_t kk0, uint32_t kk1, int k) {
  __shared__ float co[8];
  __shared__ double sm[4][10];
  int lane = threadIdx.x & 63, wid = threadIdx.x >> 6;
  if (wid == 0) {
    double S[11];
    double rv = (lane < 6) ? (double)F[k * 20 + 2 + lane] : 0.0;
    double xv = wave_solve6(SxB, lane, S, rv);
    if (lane < 6) co[lane] = (float)xv * (float)(lane + 1);
    if (lane == 6) co[6] = F[k * 20 + 0];
    if (lane == 7) co[7] = F[k * 20 + 1];
    if (blockIdx.x == 0 && lane < 6) {
      float v = (float)xv;
      out[OUT_ETA + k * 6 + lane] = v;
      if (k == NSTEP - 1) out[OUT_ETA + NSTEP * 6 + lane] = v;
      if (k >= 1) out[OUT_BP + k * 6 + lane] = (float)S[lane + 1];
    }
  }
  __syncthreads();
  int i = blockIdx.x * BLKSZ + threadIdx.x;
  double m[10];
  if (i < N_SAMP) {
    uint32_t o0, o1;
    threefry2x32(kk0, kk1, 0u, (uint32_t)i, &o0, &o1);
    float nz = bits_to_normal(o0 ^ o1);
    float x = xin[i];
    float c0 = co[0], c1 = co[1], c2 = co[2], c3 = co[3], c4 = co[4], c5 = co[5];
    float d = c0 + x * (c1 + x * (c2 + x * (c3 + x * (c4 + x * c5))));
    float y = x + co[6] * d + co[7] * nz;
    yout[i] = y;
    float pw = y;
    m[0] = (double)pw;
#pragma unroll
    for (int q = 1; q < 10; q++) { pw *= y; m[q] = (double)pw; }
  } else {
#pragma unroll
    for (int q = 0; q < 10; q++) m[q] = 0.0;
  }
  reduce10(m, SYB, lane, wid, sm);
}

// ================= corrector step k =========================================
// x[i] = y[i] + poly(y) ; accumulate S(x) into SXB.
// wave0 solves theta from SYB; block0 writes theta/dH.
__global__ __launch_bounds__(BLKSZ) void k_corr(
    const float* yin, float* xout,
    const double* __restrict__ SYB, const float* __restrict__ F,
    double* __restrict__ SXB, float* __restrict__ out, int k) {
  __shared__ float co[8];
  __shared__ double sm[4][10];
  int lane = threadIdx.x & 63, wid = threadIdx.x >> 6;
  if (wid == 0) {
    double S[11];
    // rhs = bpe - mean(moments(y)); need S first — wave_solve6 computes S then
    // consumes rv, so pre-read buckets for rhs via the same reduction inside:
    // do a first pass for S? wave_solve6 already computes S before using rv,
    // but rv is passed in. Compute S-dependent rhs by replicating the bucket
    // reduction for the needed lane only is wasteful — instead call with
    // rv = bpe and subtract inside: restructure: compute S here.
    S[0] = 1.0;
#pragma unroll
    for (int q = 0; q < 10; q++) {
      const double* p = SYB + q * NB + lane;
      double s = p[0] + p[64] + p[128] + p[192];
#pragma unroll
      for (int off = 32; off; off >>= 1) s += __shfl_xor(s, off, 64);
      S[q + 1] = s * INV_N;
    }
    int r = (lane < 6) ? lane : 0;
    double row[6];
#pragma unroll
    for (int j = 0; j < 6; j++) row[j] = (double)((r + 1) * (j + 1)) * S[r + j];
    row[r] *= 1.001;
    double rv = (lane < 6) ? ((double)F[k * 20 + 8 + lane] - S[lane + 1]) : 0.0;
#pragma unroll
    for (int c = 0; c < 6; c++) {
      double pr[6], prh;
#pragma unroll
      for (int j = 0; j < 6; j++) pr[j] = __shfl(row[j], c, 64);
      prh = __shfl(rv, c, 64);
      if (lane > c && lane < 6) {
        double f = row[c] / pr[c];
#pragma unroll
        for (int j = 0; j < 6; j++) row[j] -= f * pr[j];
        rv -= f * prh;
      }
    }
    double xv = 0.0;
#pragma unroll
    for (int rr = 5; rr >= 0; rr--) {
      double cand = rv / row[rr];
      double xr = __shfl(cand, rr, 64);
      if (lane == rr) xv = xr;
      if (lane < rr) rv -= row[rr] * xr;
    }
    if (lane < 6) co[lane] = (float)xv * (float)(lane + 1);
    if (blockIdx.x == 0) {
      float h = F[k * 20 + 0];
      float denom = h * 0.25f;                 // h * SIGMA^2
      float th = (float)xv / denom;
      if (lane < 6) {
        out[OUT_TH + k * 6 + lane] = th;
        if (k == NSTEP - 1) out[OUT_TH + NSTEP * 6 + lane] = th;
      }
      // dH = -sum th_r * dtphi_r  (gather to lane 0)
      float contrib = (lane < 6) ? th * F[k * 20 + 14 + lane] : 0.0f;
#pragma unroll
      for (int off = 4; off; off >>= 1) contrib += __shfl_down(contrib, off, 64);
      if (lane == 0) {
        float dH = -contrib;
        out[OUT_DH + k] = dH;
        if (k == NSTEP - 1) out[OUT_DH + NSTEP] = dH;
      }
    }
  }
  __syncthreads();
  int i = blockIdx.x * BLKSZ + threadIdx.x;
  double m[10];
  if (i < N_SAMP) {
    float y = yin[i];
    float c0 = co[0], c1 = co[1], c2 = co[2], c3 = co[3], c4 = co[4], c5 = co[5];
    float cr = c0 + y * (c1 + y * (c2 + y * (c3 + y * (c4 + y * c5))));
    float xn = y + cr;
    xout[i] = xn;
    float pw = xn;
    m[0] = (double)pw;
#pragma unroll
    for (int q = 1; q < 10; q++) { pw *= xn; m[q] = (double)pw; }
  } else {
#pragma unroll
    for (int q = 0; q < 10; q++) m[q] = 0.0;
  }
  reduce10(m, SXB, lane, wid, sm);
}

// ================= tail: bp rows 32, 33 from S(x_final) =====================
__global__ void k_final(const double* __restrict__ SXB_last,
                        float* __restrict__ out) {
  int lane = threadIdx.x & 63;
  for (int q = 0; q < 6; q++) {
    const double* p = SXB_last + q * NB + lane * 4;
    double s = p[0] + p[1] + p[2] + p[3];
#pragma unroll
    for (int off = 32; off; off >>= 1) s += __shfl_xor(s, off, 64);
    if (lane == q) {
      float bp = (float)(s * INV_N);
      out[OUT_BP + NSTEP * 6 + q] = bp;
      out[OUT_BP + (NSTEP + 1) * 6 + q] = bp;
    }
  }
}

extern "C" void kernel_launch(void* const* d_in, const int* in_sizes, int n_in,
                              void* d_out, int out_size, void* d_ws, size_t ws_size,
                              hipStream_t stream) {
  const float* x1 = (const float*)d_in[0];
  const float* x0 = (const float*)d_in[1];
  const float* xk = (const float*)d_in[2];
  const float* t  = (const float*)d_in[3];
  float* out = (float*)d_out;

  // ws layout: JB 37*256 f64 | SYB 32*10*256 f64 | SXB 32*10*256 f64 | F 640 f32
  double* JB  = (double*)d_ws;
  double* SYB = JB + 37 * NB;
  double* SXB = SYB + NSTEP * 10 * NB;
  float*  F   = (float*)(SXB + NSTEP * 10 * NB);

  hipMemsetAsync(d_ws, 0, (size_t)((37 + 2 * NSTEP * 10) * NB * 8), stream);

  k_reduce0<<<GRID, BLKSZ, 0, stream>>>(x1, x0, xk, JB);
  k_scalars<<<1, 64, 0, stream>>>(t, JB, F, out);

  for (int k = 0; k < NSTEP; k++) {
    uint32_t kk0, kk1;
    threefry2x32(0u, 42u, 0u, (uint32_t)k, &kk0, &kk1);  // fold_in(key(42), k)
    const float* xin = (k == 0) ? xk : out;
    const double* SxB = (k == 0) ? (JB + 27 * NB) : (SXB + (k - 1) * 10 * NB);
    k_pred<<<GRID, BLKSZ, 0, stream>>>(xin, out, SxB, F, SYB + k * 10 * NB,
                                       out, kk0, kk1, k);
    k_corr<<<GRID, BLKSZ, 0, stream>>>(out, out, SYB + k * 10 * NB, F,
                                       SXB + k * 10 * NB, out, k);
  }
  k_final<<<1, 64, 0, stream>>>(SXB + (NSTEP - 1) * 10 * NB, out);
}

// Round 6
// 3267.638 us; speedup vs baseline: 1.5647x; 1.3768x over previous
//
#include <hip/hip_runtime.h>
#include <stdint.h>

#define N_SAMP  2000000
#define NTG     250000            // thread-groups of 8 elements
#define NSTEP   32
#define INV_N   (1.0/2000000.0)
#define NB      128               // reduction buckets
#define GRID    977               // ceil(NTG/256)
#define BLKSZ   256

#define OUT_BE  2000000
#define OUT_BP  2000204
#define OUT_ETA 2000408
#define OUT_TH  2000606
#define OUT_DH  2000804

// ws layout (bytes): JB 37*128 f64 | SYB 32*10*128 f64 | SXB 32*10*128 f64 |
//                    F 640 f32 | CP 32*8 f32 | CC 32*8 f32 | CTR 64 u32
#define WS_BYTES (677 * NB * 8 + (640 + 256 + 256) * 4 + 64 * 4)

// ---------------- threefry2x32 core cipher, bit-exact vs JAX ----------------
__host__ __device__ inline void threefry2x32(uint32_t k0, uint32_t k1,
                                             uint32_t c0, uint32_t c1,
                                             uint32_t* o0, uint32_t* o1) {
  uint32_t ks2 = k0 ^ k1 ^ 0x1BD11BDAu;
  uint32_t x0 = c0 + k0;
  uint32_t x1 = c1 + k1;
#define TF_ROT(x, d) (((x) << (d)) | ((x) >> (32 - (d))))
#define TF_R(a,b,c,d, ka, kb, inc) \
  x0 += x1; x1 = TF_ROT(x1, a); x1 ^= x0; \
  x0 += x1; x1 = TF_ROT(x1, b); x1 ^= x0; \
  x0 += x1; x1 = TF_ROT(x1, c); x1 ^= x0; \
  x0 += x1; x1 = TF_ROT(x1, d); x1 ^= x0; \
  x0 += (ka); x1 += (kb) + (inc);
  TF_R(13,15,26,6,  k1,  ks2, 1u)
  TF_R(17,29,16,24, ks2, k0,  2u)
  TF_R(13,15,26,6,  k0,  k1,  3u)
  TF_R(17,29,16,24, k1,  ks2, 4u)
  TF_R(13,15,26,6,  ks2, k0,  5u)
#undef TF_R
#undef TF_ROT
  *o0 = x0; *o1 = x1;
}

// bits -> N(0,1), jax.random.normal f32 path (partitionable bits pre-XOR-folded)
__device__ inline float bits_to_normal(uint32_t bits) {
  float f = __uint_as_float((bits >> 9) | 0x3f800000u) - 1.0f;
  const float lo = -0.99999994f;
  float u = f * 2.0f + lo;
  u = fmaxf(lo, u);
  float w = -log1pf(-u * u);
  float p;
  if (w < 5.0f) {
    w = w - 2.5f;
    p = 2.81022636e-08f;
    p = fmaf(p, w, 3.43273939e-07f);
    p = fmaf(p, w, -3.5233877e-06f);
    p = fmaf(p, w, -4.39150654e-06f);
    p = fmaf(p, w, 0.00021858087f);
    p = fmaf(p, w, -0.00125372503f);
    p = fmaf(p, w, -0.00417768164f);
    p = fmaf(p, w, 0.246640727f);
    p = fmaf(p, w, 1.50140941f);
  } else {
    w = sqrtf(w) - 3.0f;
    p = -0.000200214257f;
    p = fmaf(p, w, 0.000100950558f);
    p = fmaf(p, w, 0.00134934322f);
    p = fmaf(p, w, -0.00367342844f);
    p = fmaf(p, w, 0.00573950773f);
    p = fmaf(p, w, -0.0076224613f);
    p = fmaf(p, w, 0.00943887047f);
    p = fmaf(p, w, 1.00167406f);
    p = fmaf(p, w, 2.83297682f);
  }
  return __uint_as_float(0x3FB504F3u) * (p * u);
}

__device__ inline double aload(const double* p) {
  return __hip_atomic_load(p, __ATOMIC_RELAXED, __HIP_MEMORY_SCOPE_AGENT);
}

// lane-distributed 6x6 Gaussian elimination across wave 0 (lanes 0..63).
// S[0..10] replicated mean-moments; rv = per-lane rhs (lane<6). Lane r<6
// returns solution[r]; other lanes return 0.
__device__ inline double wave_gauss6(const double S[11], double rv, int lane) {
  int r = (lane < 6) ? lane : 0;
  double row[6];
#pragma unroll
  for (int j = 0; j < 6; j++) row[j] = (double)((r + 1) * (j + 1)) * S[r + j];
  row[r] *= 1.001;                        // REG = (1e-3, 0, 0)
#pragma unroll
  for (int c = 0; c < 6; c++) {
    double pr[6], prh;
#pragma unroll
    for (int j = 0; j < 6; j++) pr[j] = __shfl(row[j], c, 64);
    prh = __shfl(rv, c, 64);
    if (lane > c && lane < 6) {
      double f = row[c] / pr[c];
#pragma unroll
      for (int j = 0; j < 6; j++) row[j] -= f * pr[j];
      rv -= f * prh;
    }
  }
  double xv = 0.0;
#pragma unroll
  for (int rr = 5; rr >= 0; rr--) {
    double cand = rv / row[rr];
    double xr = __shfl(cand, rr, 64);
    if (lane == rr) xv = xr;
    if (lane < rr) rv -= row[rr] * xr;
  }
  return xv;
}

// reduce 128 buckets x 10 quantities -> replicated means S[1..10]
__device__ inline void bucket_S(const double* __restrict__ B, int lane,
                                double S[11]) {
  S[0] = 1.0;
#pragma unroll
  for (int q = 0; q < 10; q++) {
    double s = aload(B + q * NB + lane) + aload(B + q * NB + lane + 64);
#pragma unroll
    for (int off = 32; off; off >>= 1) s += __shfl_xor(s, off, 64);
    S[q + 1] = s * INV_N;
  }
}

// block-reduce 10 f64 + bucket atomics; then last-block detection.
// Returns true (in smem flag) if this block is last.
__device__ inline int reduce10_and_mark(double md[10], double* __restrict__ buck,
                                        unsigned* __restrict__ ctr,
                                        int lane, int wid, double sm[4][10],
                                        int* islast) {
#pragma unroll
  for (int q = 0; q < 10; q++) {
    double v = md[q];
#pragma unroll
    for (int off = 32; off; off >>= 1) v += __shfl_down(v, off, 64);
    if (lane == 0) sm[wid][q] = v;
  }
  __syncthreads();
  if (threadIdx.x < 10) {
    double s = sm[0][threadIdx.x] + sm[1][threadIdx.x] +
               sm[2][threadIdx.x] + sm[3][threadIdx.x];
    atomicAdd(&buck[threadIdx.x * NB + (blockIdx.x & (NB - 1))], s);
  }
  if (threadIdx.x == 0) {
    __threadfence();
    unsigned old = __hip_atomic_fetch_add(ctr, 1u, __ATOMIC_ACQ_REL,
                                          __HIP_MEMORY_SCOPE_AGENT);
    *islast = (old == gridDim.x - 1) ? 1 : 0;
  }
  __syncthreads();
  return *islast;
}

// ================= setup: 27 joint (x0,x1) + 10 x_k moments =================
__global__ __launch_bounds__(BLKSZ) void k_reduce0(
    const float* __restrict__ x1g, const float* __restrict__ x0g,
    const float* __restrict__ xkg, double* __restrict__ JB) {
  __shared__ double sm[4][37];
  int tg = blockIdx.x * BLKSZ + threadIdx.x;
  int lane = threadIdx.x & 63, wid = threadIdx.x >> 6;
  float a32[37];
#pragma unroll
  for (int q = 0; q < 37; q++) a32[q] = 0.f;
  if (tg < NTG) {
    const float4* p0v = (const float4*)x0g + (size_t)tg * 2;
    const float4* p1v = (const float4*)x1g + (size_t)tg * 2;
    const float4* pkv = (const float4*)xkg + (size_t)tg * 2;
    float4 A0 = p0v[0], B0 = p0v[1];
    float4 A1 = p1v[0], B1 = p1v[1];
    float4 AK = pkv[0], BK = pkv[1];
    float x0s[8] = {A0.x, A0.y, A0.z, A0.w, B0.x, B0.y, B0.z, B0.w};
    float x1s[8] = {A1.x, A1.y, A1.z, A1.w, B1.x, B1.y, B1.z, B1.w};
    float xks[8] = {AK.x, AK.y, AK.z, AK.w, BK.x, BK.y, BK.z, BK.w};
#pragma unroll
    for (int j = 0; j < 8; j++) {
      float p0[7], p1[7];
      p0[0] = 1.f; p1[0] = 1.f;
#pragma unroll
      for (int m = 0; m < 6; m++) { p0[m+1] = p0[m]*x0s[j]; p1[m+1] = p1[m]*x1s[j]; }
      int q = 0;
#pragma unroll
      for (int s = 1; s <= 6; s++)
#pragma unroll
        for (int a = 0; a <= s; a++) a32[q++] += p0[a] * p1[s - a];
      float xp = xks[j];
      a32[27] += xp;
#pragma unroll
      for (int m = 1; m < 10; m++) { xp *= xks[j]; a32[27 + m] += xp; }
    }
  }
#pragma unroll
  for (int q = 0; q < 37; q++) {
    double v = (double)a32[q];
#pragma unroll
    for (int off = 32; off; off >>= 1) v += __shfl_down(v, off, 64);
    if (lane == 0) sm[wid][q] = v;
  }
  __syncthreads();
  if (threadIdx.x < 37) {
    double s = sm[0][threadIdx.x] + sm[1][threadIdx.x] +
               sm[2][threadIdx.x] + sm[3][threadIdx.x];
    atomicAdd(&JB[threadIdx.x * NB + (blockIdx.x & (NB - 1))], s);
  }
}

// ================= scalar table + BE rows + row0 + eta_0 ====================
__global__ void k_scalars(const float* __restrict__ tg_,
                          const double* __restrict__ JB,
                          float* __restrict__ F, float* __restrict__ CP,
                          float* __restrict__ out) {
  __shared__ double Msc[37];
  __shared__ float sF[8];
  int lane = threadIdx.x & 63;
  for (int q = 0; q < 37; q++) {
    double s = aload(JB + q * NB + lane) + aload(JB + q * NB + lane + 64);
#pragma unroll
    for (int off = 32; off; off >>= 1) s += __shfl_xor(s, off, 64);
    if (lane == 0) Msc[q] = s * INV_N;
  }
  __syncthreads();
#define MG(A, B_) (((A) == 0 && (B_) == 0) ? 1.0 : \
    Msc[(((A) + (B_) + 2) * ((A) + (B_) - 1)) / 2 + (A)])
  int k = threadIdx.x;
  if (k < NSTEP) {
    const double Bd[7][7] = {
        {1, 0, 0, 0, 0, 0, 0},  {1, 1, 0, 0, 0, 0, 0},   {1, 2, 1, 0, 0, 0, 0},
        {1, 3, 3, 1, 0, 0, 0},  {1, 4, 6, 4, 1, 0, 0},   {1, 5, 10, 10, 5, 1, 0},
        {1, 6, 15, 20, 15, 6, 1}};
    float tk = tg_[k], tk1 = tg_[k + 1];
    float h = tk1 - tk;
    float ns = sqrtf(2.0f * h) * 0.5f;
    const float PI_F = 3.14159274f;
    double a  = (double)cosf((PI_F * tk) * 0.5f);
    double b  = (double)sinf((PI_F * tk) * 0.5f);
    double a1 = (double)cosf((PI_F * tk1) * 0.5f);
    double b1 = (double)sinf((PI_F * tk1) * 0.5f);
    const double C2 = (double)1.57079637f;
    double pa[7], pb[7], pa1[7], pb1[7];
    pa[0] = pb[0] = pa1[0] = pb1[0] = 1.0;
    for (int i = 1; i < 7; i++) {
      pa[i] = pa[i - 1] * a;    pb[i] = pb[i - 1] * b;
      pa1[i] = pa1[i - 1] * a1; pb1[i] = pb1[i - 1] * b1;
    }
    F[k * 20 + 0] = h;
    F[k * 20 + 1] = ns;
    if (k == 0) { sF[6] = h; sF[7] = ns; }
    for (int p = 1; p <= 6; p++) {
      double s_rhs = 0, s_bpe = 0, s_dt = 0;
      for (int j = 0; j < p; j++) {
        double term = -b * MG(j + 1, p - 1 - j) + a * MG(j, p - j);
        s_rhs += Bd[p - 1][j] * pa[j]  * pb[p - 1 - j]  * term;
        s_dt  += Bd[p - 1][j] * pa1[j] * pb1[p - 1 - j] * term;
      }
      for (int j = 0; j <= p; j++)
        s_bpe += Bd[p][j] * pa1[j] * pb1[p - j] * MG(j, p - j);
      float fr = (float)((double)p * C2 * s_rhs);
      float be = (float)s_bpe;
      F[k * 20 + 2 + p - 1]  = fr;
      F[k * 20 + 8 + p - 1]  = be;
      F[k * 20 + 14 + p - 1] = (float)((double)p * C2 * s_dt);
      if (k == 0) sF[p - 1] = fr;
      out[OUT_BE + (k + 1) * 6 + (p - 1)] = be;
      if (k == NSTEP - 1) out[OUT_BE + (NSTEP + 1) * 6 + (p - 1)] = be;
    }
  }
  if (threadIdx.x < 6) {  // row 0: moments of x_0 and of x_k
    int p = threadIdx.x + 1;
    out[OUT_BE + threadIdx.x] = (float)MG(p, 0);
    out[OUT_BP + threadIdx.x] = (float)Msc[27 + threadIdx.x];
  }
#undef MG
  __syncthreads();
  // eta_0 solve from x_k moments (Msc[27..36])
  {
    double S[11];
    S[0] = 1.0;
#pragma unroll
    for (int q = 0; q < 10; q++) S[q + 1] = Msc[27 + q];
    double rv = (lane < 6) ? (double)sF[lane] : 0.0;
    double xv = wave_gauss6(S, rv, lane);
    if (lane < 6) {
      out[OUT_ETA + lane] = (float)xv;
      CP[lane] = (float)xv * (float)(lane + 1);
    }
    if (lane == 6) CP[6] = sF[6];
    if (lane == 7) CP[7] = sF[7];
  }
}

// ================= predictor step k =========================================
__global__ __launch_bounds__(BLKSZ) void k_pred(
    const float* xin, float* yout,
    const float* __restrict__ CPk, const float* __restrict__ F,
    double* __restrict__ SYBk, float* __restrict__ CCk,
    float* __restrict__ out, unsigned* __restrict__ ctr,
    uint32_t kk0, uint32_t kk1, int k) {
  __shared__ double sm[4][10];
  __shared__ int islast;
  int tg = blockIdx.x * BLKSZ + threadIdx.x;
  int lane = threadIdx.x & 63, wid = threadIdx.x >> 6;
  float4 cA = ((const float4*)CPk)[0];
  float4 cB = ((const float4*)CPk)[1];
  float c0 = cA.x, c1 = cA.y, c2 = cA.z, c3 = cA.w;
  float c4 = cB.x, c5 = cB.y, h = cB.z, ns = cB.w;
  float a32[10];
#pragma unroll
  for (int q = 0; q < 10; q++) a32[q] = 0.f;
  if (tg < NTG) {
    const float4* xi = (const float4*)xin + (size_t)tg * 2;
    float4 XA = xi[0], XB = xi[1];
    float xs[8] = {XA.x, XA.y, XA.z, XA.w, XB.x, XB.y, XB.z, XB.w};
    float ys[8];
    uint32_t base = (uint32_t)tg * 8u;
#pragma unroll
    for (int j = 0; j < 8; j++) {
      uint32_t o0, o1;
      threefry2x32(kk0, kk1, 0u, base + (uint32_t)j, &o0, &o1);
      float nz = bits_to_normal(o0 ^ o1);
      float x = xs[j];
      float d = c0 + x * (c1 + x * (c2 + x * (c3 + x * (c4 + x * c5))));
      float y = x + h * d + ns * nz;
      ys[j] = y;
      float pw = y;
      a32[0] += pw;
#pragma unroll
      for (int m = 1; m < 10; m++) { pw *= y; a32[m] += pw; }
    }
    float4* yo = (float4*)yout + (size_t)tg * 2;
    yo[0] = make_float4(ys[0], ys[1], ys[2], ys[3]);
    yo[1] = make_float4(ys[4], ys[5], ys[6], ys[7]);
  }
  double md[10];
#pragma unroll
  for (int q = 0; q < 10; q++) md[q] = (double)a32[q];
  if (reduce10_and_mark(md, SYBk, ctr, lane, wid, sm, &islast) && wid == 0) {
    __threadfence();
    double S[11];
    bucket_S(SYBk, lane, S);
    double rv = (lane < 6) ? ((double)F[k * 20 + 8 + lane] - S[lane + 1]) : 0.0;
    double xv = wave_gauss6(S, rv, lane);
    if (lane < 6) CCk[lane] = (float)xv * (float)(lane + 1);
    float hh = F[k * 20 + 0];
    float th = (float)xv / (hh * 0.25f);
    if (lane < 6) {
      out[OUT_TH + k * 6 + lane] = th;
      if (k == NSTEP - 1) out[OUT_TH + NSTEP * 6 + lane] = th;
    }
    float contrib = (lane < 6) ? th * F[k * 20 + 14 + lane] : 0.f;
#pragma unroll
    for (int off = 4; off; off >>= 1) contrib += __shfl_down(contrib, off, 64);
    if (lane == 0) {
      float dH = -contrib;
      out[OUT_DH + k] = dH;
      if (k == NSTEP - 1) out[OUT_DH + NSTEP] = dH;
    }
  }
}

// ================= corrector step k =========================================
__global__ __launch_bounds__(BLKSZ) void k_corr(
    const float* yin, float* xout,
    const float* __restrict__ CCk, const float* __restrict__ F,
    double* __restrict__ SXBk, float* __restrict__ CPn,
    float* __restrict__ out, unsigned* __restrict__ ctr, int k) {
  __shared__ double sm[4][10];
  __shared__ int islast;
  int tg = blockIdx.x * BLKSZ + threadIdx.x;
  int lane = threadIdx.x & 63, wid = threadIdx.x >> 6;
  float4 cA = ((const float4*)CCk)[0];
  float4 cB = ((const float4*)CCk)[1];
  float c0 = cA.x, c1 = cA.y, c2 = cA.z, c3 = cA.w;
  float c4 = cB.x, c5 = cB.y;
  float a32[10];
#pragma unroll
  for (int q = 0; q < 10; q++) a32[q] = 0.f;
  if (tg < NTG) {
    const float4* yi = (const float4*)yin + (size_t)tg * 2;
    float4 YA = yi[0], YB = yi[1];
    float ysv[8] = {YA.x, YA.y, YA.z, YA.w, YB.x, YB.y, YB.z, YB.w};
    float xsn[8];
#pragma unroll
    for (int j = 0; j < 8; j++) {
      float y = ysv[j];
      float cr = c0 + y * (c1 + y * (c2 + y * (c3 + y * (c4 + y * c5))));
      float xn = y + cr;
      xsn[j] = xn;
      float pw = xn;
      a32[0] += pw;
#pragma unroll
      for (int m = 1; m < 10; m++) { pw *= xn; a32[m] += pw; }
    }
    float4* xo = (float4*)xout + (size_t)tg * 2;
    xo[0] = make_float4(xsn[0], xsn[1], xsn[2], xsn[3]);
    xo[1] = make_float4(xsn[4], xsn[5], xsn[6], xsn[7]);
  }
  double md[10];
#pragma unroll
  for (int q = 0; q < 10; q++) md[q] = (double)a32[q];
  if (reduce10_and_mark(md, SXBk, ctr, lane, wid, sm, &islast) && wid == 0) {
    __threadfence();
    double S[11];
    bucket_S(SXBk, lane, S);
    if (lane < 6) {
      float bp = (float)S[lane + 1];
      out[OUT_BP + (k + 1) * 6 + lane] = bp;
      if (k == NSTEP - 1) out[OUT_BP + (NSTEP + 1) * 6 + lane] = bp;
    }
    if (k < NSTEP - 1) {
      double rv = (lane < 6) ? (double)F[(k + 1) * 20 + 2 + lane] : 0.0;
      double xv = wave_gauss6(S, rv, lane);
      if (lane < 6) {
        float v = (float)xv;
        out[OUT_ETA + (k + 1) * 6 + lane] = v;
        if (k == NSTEP - 2) out[OUT_ETA + NSTEP * 6 + lane] = v;
        CPn[lane] = v * (float)(lane + 1);
      }
      if (lane == 6) CPn[6] = F[(k + 1) * 20 + 0];
      if (lane == 7) CPn[7] = F[(k + 1) * 20 + 1];
    }
  }
}

extern "C" void kernel_launch(void* const* d_in, const int* in_sizes, int n_in,
                              void* d_out, int out_size, void* d_ws, size_t ws_size,
                              hipStream_t stream) {
  const float* x1 = (const float*)d_in[0];
  const float* x0 = (const float*)d_in[1];
  const float* xk = (const float*)d_in[2];
  const float* t  = (const float*)d_in[3];
  float* out = (float*)d_out;

  double* JB  = (double*)d_ws;
  double* SYB = JB + 37 * NB;
  double* SXB = SYB + NSTEP * 10 * NB;
  float*  F   = (float*)(SXB + NSTEP * 10 * NB);
  float*  CP  = F + 640;
  float*  CC  = CP + 256;
  unsigned* CTR = (unsigned*)(CC + 256);

  hipMemsetAsync(d_ws, 0, (size_t)WS_BYTES, stream);

  k_reduce0<<<GRID, BLKSZ, 0, stream>>>(x1, x0, xk, JB);
  k_scalars<<<1, 64, 0, stream>>>(t, JB, F, CP, out);

  for (int k = 0; k < NSTEP; k++) {
    uint32_t kk0, kk1;
    threefry2x32(0u, 42u, 0u, (uint32_t)k, &kk0, &kk1);  // fold_in(key(42), k)
    const float* xin = (k == 0) ? xk : out;
    k_pred<<<GRID, BLKSZ, 0, stream>>>(xin, out, CP + k * 8, F,
                                       SYB + k * 10 * NB, CC + k * 8,
                                       out, CTR + 2 * k, kk0, kk1, k);
    k_corr<<<GRID, BLKSZ, 0, stream>>>(out, out, CC + k * 8, F,
                                       SXB + k * 10 * NB, CP + (k + 1 < NSTEP ? k + 1 : 0) * 8,
                                       out, CTR + 2 * k + 1, k);
  }
}

// Round 7
// 1167.416 us; speedup vs baseline: 4.3796x; 2.7990x over previous
//
#include <hip/hip_runtime.h>
#include <stdint.h>

#define N_SAMP  2000000
#define NF4     500000          // float4 groups
#define NSTEP   32
#define INV_N   (1.0/2000000.0)
#define NBUCK   64
#define NWORK   511
#define GRID    512
#define BLKSZ   256

#define OUT_BE  2000000
#define OUT_BP  2000204
#define OUT_ETA 2000408
#define OUT_TH  2000606
#define OUT_DH  2000804

// ws doubles layout
#define O_JB    0
#define O_SYB   (37*NBUCK)
#define O_SXB   (O_SYB + NSTEP*10*NBUCK)
#define O_END   (O_SXB + NSTEP*10*NBUCK)      // 43328 doubles
// u32 region (after doubles): [0..7] COEFP f32, [8..15] COEFC f32,
// [16] seqP, [17] seqC, [32..63] leaf0, [64..95] leafP, [96..127] leafC
#define WS_BYTES (O_END*8 + 128*4)

#define CFENCE() __atomic_signal_fence(__ATOMIC_SEQ_CST)
#define WAITVM() __builtin_amdgcn_s_waitcnt(0)

__device__ inline uint32_t uld(const uint32_t* p) {
  return __hip_atomic_load(p, __ATOMIC_RELAXED, __HIP_MEMORY_SCOPE_AGENT);
}
__device__ inline void ust(uint32_t* p, uint32_t v) {
  __hip_atomic_store(p, v, __ATOMIC_RELAXED, __HIP_MEMORY_SCOPE_AGENT);
}
__device__ inline void uadd(uint32_t* p, uint32_t v) {
  __hip_atomic_fetch_add(p, v, __ATOMIC_RELAXED, __HIP_MEMORY_SCOPE_AGENT);
}
__device__ inline double dld(const double* p) {
  return __hip_atomic_load(p, __ATOMIC_RELAXED, __HIP_MEMORY_SCOPE_AGENT);
}
__device__ inline float fld(const float* p) {
  return __hip_atomic_load(p, __ATOMIC_RELAXED, __HIP_MEMORY_SCOPE_AGENT);
}
__device__ inline void fst(float* p, float v) {
  __hip_atomic_store(p, v, __ATOMIC_RELAXED, __HIP_MEMORY_SCOPE_AGENT);
}

// ---------------- threefry2x32 core cipher, bit-exact vs JAX ----------------
__host__ __device__ inline void threefry2x32(uint32_t k0, uint32_t k1,
                                             uint32_t c0, uint32_t c1,
                                             uint32_t* o0, uint32_t* o1) {
  uint32_t ks2 = k0 ^ k1 ^ 0x1BD11BDAu;
  uint32_t x0 = c0 + k0;
  uint32_t x1 = c1 + k1;
#define TF_ROT(x, d) (((x) << (d)) | ((x) >> (32 - (d))))
#define TF_R(a,b,c,d, ka, kb, inc) \
  x0 += x1; x1 = TF_ROT(x1, a); x1 ^= x0; \
  x0 += x1; x1 = TF_ROT(x1, b); x1 ^= x0; \
  x0 += x1; x1 = TF_ROT(x1, c); x1 ^= x0; \
  x0 += x1; x1 = TF_ROT(x1, d); x1 ^= x0; \
  x0 += (ka); x1 += (kb) + (inc);
  TF_R(13,15,26,6,  k1,  ks2, 1u)
  TF_R(17,29,16,24, ks2, k0,  2u)
  TF_R(13,15,26,6,  k0,  k1,  3u)
  TF_R(17,29,16,24, k1,  ks2, 4u)
  TF_R(13,15,26,6,  ks2, k0,  5u)
#undef TF_R
#undef TF_ROT
  *o0 = x0; *o1 = x1;
}

// bits -> N(0,1), jax.random.normal f32 path (partitionable bits pre-XOR-folded)
__device__ inline float bits_to_normal(uint32_t bits) {
  float f = __uint_as_float((bits >> 9) | 0x3f800000u) - 1.0f;
  const float lo = -0.99999994f;
  float u = f * 2.0f + lo;
  u = fmaxf(lo, u);
  float w = -log1pf(-u * u);
  float p;
  if (w < 5.0f) {
    w = w - 2.5f;
    p = 2.81022636e-08f;
    p = fmaf(p, w, 3.43273939e-07f);
    p = fmaf(p, w, -3.5233877e-06f);
    p = fmaf(p, w, -4.39150654e-06f);
    p = fmaf(p, w, 0.00021858087f);
    p = fmaf(p, w, -0.00125372503f);
    p = fmaf(p, w, -0.00417768164f);
    p = fmaf(p, w, 0.246640727f);
    p = fmaf(p, w, 1.50140941f);
  } else {
    w = sqrtf(w) - 3.0f;
    p = -0.000200214257f;
    p = fmaf(p, w, 0.000100950558f);
    p = fmaf(p, w, 0.00134934322f);
    p = fmaf(p, w, -0.00367342844f);
    p = fmaf(p, w, 0.00573950773f);
    p = fmaf(p, w, -0.0076224613f);
    p = fmaf(p, w, 0.00943887047f);
    p = fmaf(p, w, 1.00167406f);
    p = fmaf(p, w, 2.83297682f);
  }
  return __uint_as_float(0x3FB504F3u) * (p * u);
}

// lane-distributed 6x6 Gaussian elimination (wave 0). S replicated; rv = rhs
// for lane<6. Lane r<6 returns solution[r].
__device__ inline double wave_gauss6(const double S[11], double rv, int lane) {
  int r = (lane < 6) ? lane : 0;
  double row[6];
#pragma unroll
  for (int j = 0; j < 6; j++) row[j] = (double)((r + 1) * (j + 1)) * S[r + j];
  row[r] *= 1.001;                        // REG = (1e-3, 0, 0)
#pragma unroll
  for (int c = 0; c < 6; c++) {
    double pr[6], prh;
#pragma unroll
    for (int j = 0; j < 6; j++) pr[j] = __shfl(row[j], c, 64);
    prh = __shfl(rv, c, 64);
    if (lane > c && lane < 6) {
      double f = row[c] / pr[c];
#pragma unroll
      for (int j = 0; j < 6; j++) row[j] -= f * pr[j];
      rv -= f * prh;
    }
  }
  double xv = 0.0;
#pragma unroll
  for (int rr = 5; rr >= 0; rr--) {
    double cand = rv / row[rr];
    double xr = __shfl(cand, rr, 64);
    if (lane == rr) xv = xr;
    if (lane < rr) rv -= row[rr] * xr;
  }
  return xv;
}

// solver: wait until sum of 32 leaf counters reaches target
__device__ inline void wait_leaves(const uint32_t* leaf, uint32_t target, int lane) {
  for (;;) {
    uint32_t v = uld(&leaf[lane & 31]);           // both halves read same 32
#pragma unroll
    for (int off = 16; off; off >>= 1) v += __shfl_xor(v, off, 64);
    if (v >= target) break;
    __builtin_amdgcn_s_sleep(4);
  }
  CFENCE();
}

// solver: replicated mean-moments from 64 buckets x 10 quantities
__device__ inline void get_S(const double* B, int lane, double S[11]) {
  S[0] = 1.0;
#pragma unroll
  for (int q = 0; q < 10; q++) {
    double s = dld(&B[q * NBUCK + lane]);
#pragma unroll
    for (int off = 32; off; off >>= 1) s += __shfl_xor(s, off, 64);
    S[q + 1] = s * INV_N;
  }
}

__global__ __launch_bounds__(BLKSZ, 2) void k_all(
    const float* __restrict__ x1g, const float* __restrict__ x0g,
    const float* __restrict__ xkg, const float* __restrict__ tg,
    float* __restrict__ out, double* __restrict__ WD, uint32_t* __restrict__ WU) {
  __shared__ double sm[4][37];
  __shared__ float sC[8];
  __shared__ double sMsc[37];
  __shared__ float sF[NSTEP * 20];

  const int t = threadIdx.x;
  const int lane = t & 63, wid = t >> 6;
  double* JB  = WD + O_JB;
  double* SYB = WD + O_SYB;
  double* SXB = WD + O_SXB;
  float* COEFP = (float*)WU;
  float* COEFC = (float*)(WU + 8);
  uint32_t* seqP = WU + 16;
  uint32_t* seqC = WU + 17;
  uint32_t* leaf0 = WU + 32;
  uint32_t* leafP = WU + 64;
  uint32_t* leafC = WU + 96;

  if (blockIdx.x == 0) {
    // =========================== SOLVER (wave 0) ===========================
    if (t >= 64) return;
    // ---- setup: wait all workers' joint-moment buckets
    wait_leaves(leaf0, NWORK, lane);
    for (int q = 0; q < 37; q++) {
      double s = dld(&JB[q * NBUCK + lane]);
#pragma unroll
      for (int off = 32; off; off >>= 1) s += __shfl_xor(s, off, 64);
      if (lane == 0) sMsc[q] = s * INV_N;
    }
    // ---- F table (lane k handles step k), BE rows, row-0 outputs
#define MG(A, B_) (((A) == 0 && (B_) == 0) ? 1.0 : \
    sMsc[(((A) + (B_) + 2) * ((A) + (B_) - 1)) / 2 + (A)])
    if (lane < NSTEP) {
      const double Bd[7][7] = {
          {1,0,0,0,0,0,0},{1,1,0,0,0,0,0},{1,2,1,0,0,0,0},{1,3,3,1,0,0,0},
          {1,4,6,4,1,0,0},{1,5,10,10,5,1,0},{1,6,15,20,15,6,1}};
      int k = lane;
      float tk = tg[k], tk1 = tg[k + 1];
      float h = tk1 - tk;
      float ns = sqrtf(2.0f * h) * 0.5f;
      const float PI_F = 3.14159274f;
      double a  = (double)cosf((PI_F * tk) * 0.5f);
      double b  = (double)sinf((PI_F * tk) * 0.5f);
      double a1 = (double)cosf((PI_F * tk1) * 0.5f);
      double b1 = (double)sinf((PI_F * tk1) * 0.5f);
      const double C2 = (double)1.57079637f;
      double pa[7], pb[7], pa1[7], pb1[7];
      pa[0] = pb[0] = pa1[0] = pb1[0] = 1.0;
      for (int i = 1; i < 7; i++) {
        pa[i] = pa[i-1] * a;   pb[i] = pb[i-1] * b;
        pa1[i] = pa1[i-1] * a1; pb1[i] = pb1[i-1] * b1;
      }
      sF[k * 20 + 0] = h;
      sF[k * 20 + 1] = ns;
      for (int p = 1; p <= 6; p++) {
        double s_rhs = 0, s_bpe = 0, s_dt = 0;
        for (int j = 0; j < p; j++) {
          double term = -b * MG(j + 1, p - 1 - j) + a * MG(j, p - j);
          s_rhs += Bd[p-1][j] * pa[j]  * pb[p-1-j]  * term;
          s_dt  += Bd[p-1][j] * pa1[j] * pb1[p-1-j] * term;
        }
        for (int j = 0; j <= p; j++)
          s_bpe += Bd[p][j] * pa1[j] * pb1[p - j] * MG(j, p - j);
        float fr = (float)((double)p * C2 * s_rhs);
        float be = (float)s_bpe;
        sF[k * 20 + 2 + p - 1]  = fr;
        sF[k * 20 + 8 + p - 1]  = be;
        sF[k * 20 + 14 + p - 1] = (float)((double)p * C2 * s_dt);
        out[OUT_BE + (k + 1) * 6 + (p - 1)] = be;
        if (k == NSTEP - 1) out[OUT_BE + (NSTEP + 1) * 6 + (p - 1)] = be;
      }
    }
    if (lane < 6) {  // row 0: moments of x_0 and of x_k
      int p = lane + 1;
      out[OUT_BE + lane] = (float)MG(p, 0);
      out[OUT_BP + lane] = (float)sMsc[27 + lane];
    }
#undef MG
    // ---- eta_0 solve from x_k moments, publish pred coefs for step 0
    {
      double S[11];
      S[0] = 1.0;
#pragma unroll
      for (int q = 0; q < 10; q++) S[q + 1] = sMsc[27 + q];
      double rv = (lane < 6) ? (double)sF[2 + lane] : 0.0;
      double xv = wave_gauss6(S, rv, lane);
      if (lane < 6) {
        out[OUT_ETA + lane] = (float)xv;
        fst(&COEFP[lane], (float)xv * (float)(lane + 1));
      }
      if (lane == 6) fst(&COEFP[6], sF[0]);
      if (lane == 7) fst(&COEFP[7], sF[1]);
      CFENCE(); WAITVM();
      if (lane == 0) ust(seqP, 1u);
    }
    // ---- main loop
    for (int k = 0; k < NSTEP; k++) {
      // theta solve after all pred buckets of step k
      wait_leaves(leafP, (uint32_t)(NWORK * (k + 1)), lane);
      {
        double S[11];
        get_S(SYB + k * 10 * NBUCK, lane, S);
        double rv = (lane < 6) ? ((double)sF[k*20 + 8 + lane] - S[lane + 1]) : 0.0;
        double xv = wave_gauss6(S, rv, lane);
        if (lane < 6) fst(&COEFC[lane], (float)xv * (float)(lane + 1));
        float h = sF[k * 20];
        float th = (float)xv / (h * 0.25f);
        if (lane < 6) {
          out[OUT_TH + k * 6 + lane] = th;
          if (k == NSTEP - 1) out[OUT_TH + NSTEP * 6 + lane] = th;
        }
        float contrib = (lane < 6) ? th * sF[k*20 + 14 + lane] : 0.f;
#pragma unroll
        for (int off = 4; off; off >>= 1) contrib += __shfl_down(contrib, off, 64);
        if (lane == 0) {
          float dH = -contrib;
          out[OUT_DH + k] = dH;
          if (k == NSTEP - 1) out[OUT_DH + NSTEP] = dH;
        }
        CFENCE(); WAITVM();
        if (lane == 0) ust(seqC, (uint32_t)(k + 1));
      }
      // eta_{k+1} solve after all corr buckets of step k
      wait_leaves(leafC, (uint32_t)(NWORK * (k + 1)), lane);
      {
        double S[11];
        get_S(SXB + k * 10 * NBUCK, lane, S);
        if (lane < 6) {
          float bp = (float)S[lane + 1];
          out[OUT_BP + (k + 1) * 6 + lane] = bp;
          if (k == NSTEP - 1) out[OUT_BP + (NSTEP + 1) * 6 + lane] = bp;
        }
        if (k < NSTEP - 1) {
          double rv = (lane < 6) ? (double)sF[(k+1)*20 + 2 + lane] : 0.0;
          double xv = wave_gauss6(S, rv, lane);
          if (lane < 6) {
            float v = (float)xv;
            out[OUT_ETA + (k + 1) * 6 + lane] = v;
            if (k + 1 == NSTEP - 1) out[OUT_ETA + NSTEP * 6 + lane] = v;
            fst(&COEFP[lane], v * (float)(lane + 1));
          }
          if (lane == 6) fst(&COEFP[6], sF[(k+1) * 20 + 0]);
          if (lane == 7) fst(&COEFP[7], sF[(k+1) * 20 + 1]);
          CFENCE(); WAITVM();
          if (lane == 0) ust(seqP, (uint32_t)(k + 2));
        }
      }
    }
    return;
  }

  // ============================== WORKER =================================
  const int wb = blockIdx.x - 1;
  int f4[4]; bool vld[4];
  float st[16];
#pragma unroll
  for (int c = 0; c < 4; c++) { f4[c] = (wb * 4 + c) * 256 + t; vld[c] = f4[c] < NF4; }

  // ---- setup: load state + 37 joint/xk moments
  {
    float a37[37];
#pragma unroll
    for (int q = 0; q < 37; q++) a37[q] = 0.f;
#pragma unroll
    for (int c = 0; c < 4; c++) {
      if (vld[c]) {
        float4 xk4 = ((const float4*)xkg)[f4[c]];
        float4 x04 = ((const float4*)x0g)[f4[c]];
        float4 x14 = ((const float4*)x1g)[f4[c]];
        float xk_[4] = {xk4.x, xk4.y, xk4.z, xk4.w};
        float x0_[4] = {x04.x, x04.y, x04.z, x04.w};
        float x1_[4] = {x14.x, x14.y, x14.z, x14.w};
#pragma unroll
        for (int r = 0; r < 4; r++) {
          st[c * 4 + r] = xk_[r];
          float p0[7], p1[7];
          p0[0] = 1.f; p1[0] = 1.f;
#pragma unroll
          for (int m = 0; m < 6; m++) { p0[m+1] = p0[m]*x0_[r]; p1[m+1] = p1[m]*x1_[r]; }
          int q = 0;
#pragma unroll
          for (int s = 1; s <= 6; s++)
#pragma unroll
            for (int a = 0; a <= s; a++) a37[q++] += p0[a] * p1[s - a];
          float xp = xk_[r];
          a37[27] += xp;
#pragma unroll
          for (int m = 1; m < 10; m++) { xp *= xk_[r]; a37[27 + m] += xp; }
        }
      } else {
#pragma unroll
        for (int r = 0; r < 4; r++) st[c * 4 + r] = 0.f;
      }
    }
#pragma unroll
    for (int q = 0; q < 37; q++) {
      double v = (double)a37[q];
#pragma unroll
      for (int off = 32; off; off >>= 1) v += __shfl_down(v, off, 64);
      if (lane == 0) sm[wid][q] = v;
    }
    __syncthreads();
    if (t < 37) {
      double s = sm[0][t] + sm[1][t] + sm[2][t] + sm[3][t];
      atomicAdd(&JB[t * NBUCK + (blockIdx.x & (NBUCK - 1))], s);
    }
    if (t == 0) { CFENCE(); WAITVM(); uadd(&leaf0[blockIdx.x & 31], 1u); }
  }

  // ---- main loop
  for (int k = 0; k < NSTEP; k++) {
    uint32_t kk0, kk1;
    threefry2x32(0u, 42u, 0u, (uint32_t)k, &kk0, &kk1);
    // -- predictor
    if (t == 0) {
      while (uld(seqP) < (uint32_t)(k + 1)) __builtin_amdgcn_s_sleep(4);
      CFENCE();
#pragma unroll
      for (int i = 0; i < 8; i++) sC[i] = fld(&COEFP[i]);
    }
    __syncthreads();
    {
      float c0 = sC[0], c1 = sC[1], c2 = sC[2], c3 = sC[3];
      float c4 = sC[4], c5 = sC[5], h = sC[6], ns = sC[7];
      float acc[10];
#pragma unroll
      for (int q = 0; q < 10; q++) acc[q] = 0.f;
#pragma unroll
      for (int c = 0; c < 4; c++) {
        if (vld[c]) {
          uint32_t base = (uint32_t)(f4[c] * 4);
#pragma unroll
          for (int r = 0; r < 4; r++) {
            uint32_t o0, o1;
            threefry2x32(kk0, kk1, 0u, base + (uint32_t)r, &o0, &o1);
            float nz = bits_to_normal(o0 ^ o1);
            float x = st[c * 4 + r];
            float d = c0 + x*(c1 + x*(c2 + x*(c3 + x*(c4 + x*c5))));
            float y = x + h * d + ns * nz;
            st[c * 4 + r] = y;
            float pw = y;
            acc[0] += pw;
#pragma unroll
            for (int m = 1; m < 10; m++) { pw *= y; acc[m] += pw; }
          }
        }
      }
#pragma unroll
      for (int q = 0; q < 10; q++) {
        double v = (double)acc[q];
#pragma unroll
        for (int off = 32; off; off >>= 1) v += __shfl_down(v, off, 64);
        if (lane == 0) sm[wid][q] = v;
      }
      __syncthreads();
      if (t < 10) {
        double s = sm[0][t] + sm[1][t] + sm[2][t] + sm[3][t];
        atomicAdd(&SYB[k * 10 * NBUCK + t * NBUCK + (blockIdx.x & (NBUCK - 1))], s);
      }
      if (t == 0) { CFENCE(); WAITVM(); uadd(&leafP[blockIdx.x & 31], 1u); }
    }
    // -- corrector
    if (t == 0) {
      while (uld(seqC) < (uint32_t)(k + 1)) __builtin_amdgcn_s_sleep(4);
      CFENCE();
#pragma unroll
      for (int i = 0; i < 6; i++) sC[i] = fld(&COEFC[i]);
    }
    __syncthreads();
    {
      float c0 = sC[0], c1 = sC[1], c2 = sC[2], c3 = sC[3];
      float c4 = sC[4], c5 = sC[5];
      float acc[10];
#pragma unroll
      for (int q = 0; q < 10; q++) acc[q] = 0.f;
#pragma unroll
      for (int c = 0; c < 4; c++) {
        if (vld[c]) {
#pragma unroll
          for (int r = 0; r < 4; r++) {
            float y = st[c * 4 + r];
            float cr = c0 + y*(c1 + y*(c2 + y*(c3 + y*(c4 + y*c5))));
            float xn = y + cr;
            st[c * 4 + r] = xn;
            float pw = xn;
            acc[0] += pw;
#pragma unroll
            for (int m = 1; m < 10; m++) { pw *= xn; acc[m] += pw; }
          }
        }
      }
#pragma unroll
      for (int q = 0; q < 10; q++) {
        double v = (double)acc[q];
#pragma unroll
        for (int off = 32; off; off >>= 1) v += __shfl_down(v, off, 64);
        if (lane == 0) sm[wid][q] = v;
      }
      __syncthreads();
      if (t < 10) {
        double s = sm[0][t] + sm[1][t] + sm[2][t] + sm[3][t];
        atomicAdd(&SXB[k * 10 * NBUCK + t * NBUCK + (blockIdx.x & (NBUCK - 1))], s);
      }
      if (t == 0) { CFENCE(); WAITVM(); uadd(&leafC[blockIdx.x & 31], 1u); }
    }
  }

  // ---- write x_final
#pragma unroll
  for (int c = 0; c < 4; c++) {
    if (vld[c]) {
      ((float4*)out)[f4[c]] =
          make_float4(st[c*4+0], st[c*4+1], st[c*4+2], st[c*4+3]);
    }
  }
}

extern "C" void kernel_launch(void* const* d_in, const int* in_sizes, int n_in,
                              void* d_out, int out_size, void* d_ws, size_t ws_size,
                              hipStream_t stream) {
  const float* x1 = (const float*)d_in[0];
  const float* x0 = (const float*)d_in[1];
  const float* xk = (const float*)d_in[2];
  const float* t  = (const float*)d_in[3];
  float* out = (float*)d_out;

  double* WD = (double*)d_ws;
  uint32_t* WU = (uint32_t*)(WD + O_END);

  hipMemsetAsync(d_ws, 0, (size_t)WS_BYTES, stream);
  k_all<<<GRID, BLKSZ, 0, stream>>>(x1, x0, xk, t, out, WD, WU);
}